// Round 2
// baseline (1454.608 us; speedup 1.0000x reference)
//
#include <hip/hip_runtime.h>

// GAT layer: N=100000 nodes, E=1600000 edges, 4 heads, D_in=128, D_out=32.
// Input dtypes are ambiguous (reference says f32/int64; harness label says bf16),
// so we detect both float width (bf16 vs f32) and int width (int32 vs int64)
// on-device from the data and branch wave-uniformly.

typedef __attribute__((ext_vector_type(8))) short short8_t;
typedef __attribute__((ext_vector_type(4))) float float4v;

static __device__ inline float bf2f(unsigned short u) {
    return __uint_as_float(((unsigned int)u) << 16);
}
static __device__ inline unsigned short f2bf(float f) {
    unsigned int u = __float_as_uint(f);
    return (unsigned short)((u + 0x7fffu + ((u >> 16) & 1u)) >> 16);
}

// ---------------- K0: dtype detection.
// flags[0]=1 -> floats are bf16 ; flags[1]=1 -> ints are int64.
// bf16 test: word bits [14:7] are the LOW bf16's exponent field -> concentrated
// in [88,140] for N(0,1) data; for f32 those are random mantissa bits (~21% hit).
// int64 test: values < 2^31 -> every odd 32-bit word is 0.
__global__ __launch_bounds__(256) void k_detect(const unsigned int* __restrict__ hwords,
                                                const unsigned int* __restrict__ ewords,
                                                int* __restrict__ flags) {
    __shared__ int s_bf, s_zero;
    if (threadIdx.x == 0) { s_bf = 0; s_zero = 0; }
    __syncthreads();
    int c = 0;
    for (int i = threadIdx.x; i < 1024; i += 256) {
        unsigned int e = (hwords[i] >> 7) & 0xFFu;
        c += (e >= 88 && e <= 140) ? 1 : 0;
    }
    atomicAdd(&s_bf, c);
    int z = 0;
    for (int i = threadIdx.x; i < 64; i += 256) z += (ewords[2 * i + 1] == 0u) ? 1 : 0;
    atomicAdd(&s_zero, z);
    __syncthreads();
    if (threadIdx.x == 0) {
        flags[0] = (s_bf >= 700) ? 1 : 0;   // bf16 expects ~1024, f32 ~210
        flags[1] = (s_zero >= 32) ? 1 : 0;  // int64 expects 64, int32 ~0
    }
}

// ---------------- K0b: normalize edge_index to clamped int32 [2E]
__global__ void k_cvt_ei(const int* __restrict__ raw, const int* __restrict__ flags,
                         int* __restrict__ ei32, int twoE, int nmax) {
    int i = blockIdx.x * 256 + threadIdx.x;
    if (i >= twoE) return;
    int v = flags[1] ? raw[2 * (size_t)i] : raw[i];  // int64: low word at slot 2i (LE)
    v = v < 0 ? 0 : (v >= nmax ? nmax - 1 : v);
    ei32[i] = v;
}

// ---------------- K1: H_w[n][idx] = sum_k H_in[n][k] * W[idx][k], idx = h*32+o
// bf16 path: MFMA 16x16x32. A frag A[m=lane&15][k=quad*8+j]; B frag
// B[n=lane&15][k=quad*8+j]; C/D col=lane&15, row=quad*4+reg.
// f32 path: exact VALU dot products (no fp32-input MFMA on CDNA4).
__global__ __launch_bounds__(256) void k_hw(const void* __restrict__ Hin_,
                                            const void* __restrict__ W_,
                                            const int* __restrict__ flags,
                                            float* __restrict__ Hw, int nnodes) {
    bool isbf = flags[0] != 0;
    if (isbf) {
        const unsigned short* Hin = (const unsigned short*)Hin_;
        const unsigned short* Wt = (const unsigned short*)W_;
        int wave = threadIdx.x >> 6;
        int lane = threadIdx.x & 63;
        int tile = blockIdx.x * 4 + wave;  // one 16-node tile per wave
        int nbase = tile * 16;
        if (nbase >= nnodes) return;
        int mrow = lane & 15;
        int quad = lane >> 4;
        int anode = nbase + mrow;
        int nclamp = anode < nnodes ? anode : nnodes - 1;

        float4v acc[8] = {};
        const short8_t* Ap = (const short8_t*)(Hin + (size_t)nclamp * 128 + quad * 8);
        for (int kc = 0; kc < 4; ++kc) {
            short8_t a = Ap[kc * 4];  // k chunk of 32
            for (int t = 0; t < 8; ++t) {
                const short8_t* Bp =
                    (const short8_t*)(Wt + (size_t)(t * 16 + mrow) * 128 + kc * 32 + quad * 8);
                short8_t b = *Bp;
                acc[t] = __builtin_amdgcn_mfma_f32_16x16x32_bf16(a, b, acc[t], 0, 0, 0);
            }
        }
        for (int t = 0; t < 8; ++t)
            for (int r = 0; r < 4; ++r) {
                int nrow = nbase + quad * 4 + r;
                if (nrow < nnodes)
                    Hw[(size_t)nrow * 128 + t * 16 + mrow] = acc[t][r];
            }
    } else {
        const float* Hf = (const float*)Hin_;
        const float* Wf = (const float*)W_;
        int nb = blockIdx.x * 64;  // 64 nodes per block (4 waves x 16)
        for (int idx = threadIdx.x; idx < 64 * 128; idx += 256) {
            int node = nb + (idx >> 7);
            if (node >= nnodes) continue;
            int o = idx & 127;
            const float4v* h4 = (const float4v*)(Hf + (size_t)node * 128);
            const float4v* w4 = (const float4v*)(Wf + (size_t)o * 128);
            float s = 0.f;
            for (int k = 0; k < 32; ++k) {
                float4v a = h4[k], b = w4[k];
                s += a[0] * b[0] + a[1] * b[1] + a[2] * b[2] + a[3] * b[3];
            }
            Hw[(size_t)node * 128 + o] = s;
        }
    }
}

// ---------------- K1b: s_src[n][h], s_tgt[n][h] = dot(Hw[n][h*32..], A_{src,tgt}[h])
__global__ __launch_bounds__(256) void k_scores(const float* __restrict__ Hw,
                                                const void* __restrict__ Asrc_,
                                                const void* __restrict__ Atgt_,
                                                const int* __restrict__ flags,
                                                float* __restrict__ s_src,
                                                float* __restrict__ s_tgt, int nnodes) {
    __shared__ float As[128], At[128];
    bool isbf = flags[0] != 0;
    if (threadIdx.x < 128) {
        if (isbf) {
            As[threadIdx.x] = bf2f(((const unsigned short*)Asrc_)[threadIdx.x]);
            At[threadIdx.x] = bf2f(((const unsigned short*)Atgt_)[threadIdx.x]);
        } else {
            As[threadIdx.x] = ((const float*)Asrc_)[threadIdx.x];
            At[threadIdx.x] = ((const float*)Atgt_)[threadIdx.x];
        }
    }
    __syncthreads();
    int gi = blockIdx.x * 256 + threadIdx.x;
    int n = gi >> 2, h = gi & 3;
    if (n >= nnodes) return;
    const float* hw = Hw + (size_t)n * 128 + h * 32;
    float a = 0.f, b = 0.f;
    for (int o = 0; o < 32; ++o) {
        float v = hw[o];
        a += v * As[h * 32 + o];
        b += v * At[h * 32 + o];
    }
    s_src[n * 4 + h] = a;
    s_tgt[n * 4 + h] = b;
}

// ---------------- K2: in-degree histogram over targets
__global__ void k_deg(const int* __restrict__ ei32, int* __restrict__ deg, int E) {
    int i = blockIdx.x * 256 + threadIdx.x;
    if (i < E) atomicAdd(&deg[ei32[E + i]], 1);
}

// ---------------- scan helpers
__device__ inline int block_excl_scan(int v) {
    __shared__ int wsum[8];
    int lane = threadIdx.x & 63, w = threadIdx.x >> 6;
    int inc = v;
    for (int d = 1; d < 64; d <<= 1) {
        int t = __shfl_up(inc, d, 64);
        if (lane >= d) inc += t;
    }
    if (lane == 63) wsum[w] = inc;
    __syncthreads();
    int base = 0;
    for (int i = 0; i < w; ++i) base += wsum[i];
    __syncthreads();
    return base + inc - v;
}

__global__ __launch_bounds__(256) void k_blocksum(const int* __restrict__ deg,
                                                  int* __restrict__ part, int n) {
    int i = blockIdx.x * 256 + threadIdx.x;
    int v = (i < n) ? deg[i] : 0;
    int e = block_excl_scan(v);
    if (threadIdx.x == 255) part[blockIdx.x] = e + v;
}

__global__ __launch_bounds__(512) void k_scanpart(const int* __restrict__ part,
                                                  int* __restrict__ psum, int nb) {
    int v = ((int)threadIdx.x < nb) ? part[threadIdx.x] : 0;
    int e = block_excl_scan(v);
    if ((int)threadIdx.x < nb) psum[threadIdx.x] = e;
}

__global__ __launch_bounds__(256) void k_offsets(const int* __restrict__ deg,
                                                 const int* __restrict__ psum,
                                                 int* __restrict__ offs,
                                                 int* __restrict__ cursor, int n) {
    int i = blockIdx.x * 256 + threadIdx.x;
    int v = (i < n) ? deg[i] : 0;
    int e = block_excl_scan(v) + psum[blockIdx.x];
    if (i < n) {
        offs[i] = e;
        cursor[i] = e;
        if (i == n - 1) offs[n] = e + v;
    }
}

// ---------------- K4: scatter edges into CSR (store src per slot)
__global__ void k_fill(const int* __restrict__ ei32, int* __restrict__ cursor,
                       int* __restrict__ csr, int E) {
    int i = blockIdx.x * 256 + threadIdx.x;
    if (i < E) {
        int t = ei32[E + i];
        int slot = atomicAdd(&cursor[t], 1);
        csr[slot] = ei32[i];
    }
}

// ---------------- K5: per-node softmax + weighted aggregation + ELU
// One wave per node. Softmax without max-subtraction: logits bounded (~13) for
// sane data; clamp at 60 (no-op normally) so a decode error can't NaN-cascade.
__global__ __launch_bounds__(256) void k_aggr(const int* __restrict__ offs,
                                              const int* __restrict__ csr,
                                              const float* __restrict__ s_src,
                                              const float* __restrict__ s_tgt,
                                              const float* __restrict__ Hw,
                                              const int* __restrict__ flags,
                                              void* __restrict__ outv, int nnodes) {
    int wave = threadIdx.x >> 6, lane = threadIdx.x & 63;
    int n = blockIdx.x * 4 + wave;
    if (n >= nnodes) return;
    int off = offs[n];
    int deg = offs[n + 1] - off;

    const float4v* ss4 = (const float4v*)s_src;
    float4v st = ((const float4v*)s_tgt)[n];

    // phase A: sum of exp(leaky_relu(s_src[src]+s_tgt[n])) per head
    float4v se = {0.f, 0.f, 0.f, 0.f};
    for (int j = lane; j < deg; j += 64) {
        int src = csr[off + j];
        float4v ss = ss4[src];
        for (int c = 0; c < 4; ++c) {
            float x = ss[c] + st[c];
            x = fmaxf(x, 0.2f * x);  // leaky_relu(0.2)
            x = fminf(x, 60.f);
            se[c] += __expf(x);
        }
    }
    for (int d = 1; d < 64; d <<= 1)
        for (int c = 0; c < 4; ++c) se[c] += __shfl_xor(se[c], d, 64);

    int hsel = (lane >> 5) & 1;  // head parity for this lane's two elems
    float st0 = hsel ? st[1] : st[0];
    float st1 = hsel ? st[3] : st[2];
    float s0 = hsel ? se[1] : se[0];
    float s1 = hsel ? se[3] : se[2];
    float inv0 = s0 > 0.f ? 1.0f / s0 : 0.f;
    float inv1 = s1 > 0.f ? 1.0f / s1 : 0.f;

    // phase B: accumulate unnormalized exp * Hw[src], normalize once at end
    float acc0 = 0.f, acc1 = 0.f;
    for (int base = 0; base < deg; base += 64) {
        int cnt = min(64, deg - base);
        int mysrc = (base + lane < deg) ? csr[off + base + lane] : 0;
        for (int jj = 0; jj < cnt; ++jj) {
            int src = __shfl(mysrc, jj, 64);
            float4v ss = ss4[src];  // broadcast 16B
            float e0 = (hsel ? ss[1] : ss[0]) + st0;
            float e1 = (hsel ? ss[3] : ss[2]) + st1;
            e0 = fminf(fmaxf(e0, 0.2f * e0), 60.f);
            e1 = fminf(fmaxf(e1, 0.2f * e1), 60.f);
            float w0 = __expf(e0), w1 = __expf(e1);
            const float* hwrow = Hw + (size_t)src * 128;
            acc0 += w0 * hwrow[lane];       // coalesced 256B across wave
            acc1 += w1 * hwrow[64 + lane];  // coalesced 256B across wave
        }
    }
    acc0 *= inv0;
    acc1 *= inv1;
    acc0 = acc0 > 0.f ? acc0 : __expf(acc0) - 1.0f;  // elu
    acc1 = acc1 > 0.f ? acc1 : __expf(acc1) - 1.0f;

    int o = lane & 31;
    int h0 = lane >> 5, h1 = 2 + h0;
    size_t i0 = (size_t)h0 * nnodes * 32 + (size_t)n * 32 + o;
    size_t i1 = (size_t)h1 * nnodes * 32 + (size_t)n * 32 + o;
    if (flags[0]) {
        ((unsigned short*)outv)[i0] = f2bf(acc0);
        ((unsigned short*)outv)[i1] = f2bf(acc1);
    } else {
        ((float*)outv)[i0] = acc0;
        ((float*)outv)[i1] = acc1;
    }
}

extern "C" void kernel_launch(void* const* d_in, const int* in_sizes, int n_in,
                              void* d_out, int out_size, void* d_ws, size_t ws_size,
                              hipStream_t stream) {
    const void* Hin = d_in[0];
    const int* ei_raw = (const int*)d_in[1];
    const void* W = d_in[2];
    const void* Asrc = d_in[3];
    const void* Atgt = d_in[4];
    int N = in_sizes[0] / 128;
    int E = in_sizes[1] / 2;

    char* ws = (char*)d_ws;
    size_t p = 0;
    auto alloc = [&](size_t bytes) {
        void* r = ws + p;
        p = (p + bytes + 511) & ~(size_t)511;
        return r;
    };
    float* Hw = (float*)alloc((size_t)N * 128 * 4);   // 51.2 MB
    float* s_src = (float*)alloc((size_t)N * 4 * 4);  // 1.6 MB
    float* s_tgt = (float*)alloc((size_t)N * 4 * 4);  // 1.6 MB
    int* deg = (int*)alloc((size_t)N * 4);
    int* offs = (int*)alloc((size_t)(N + 1) * 4);
    int* cursor = (int*)alloc((size_t)N * 4);
    int* part = (int*)alloc(512 * 4);
    int* psum = (int*)alloc(512 * 4);
    int* csr = (int*)alloc((size_t)E * 4);     // 6.4 MB
    int* ei32 = (int*)alloc((size_t)2 * E * 4); // 12.8 MB
    int* flags = (int*)alloc(2 * 4);

    hipMemsetAsync(deg, 0, (size_t)N * 4, stream);

    k_detect<<<dim3(1), 256, 0, stream>>>((const unsigned int*)Hin,
                                          (const unsigned int*)ei_raw, flags);
    k_cvt_ei<<<dim3((2 * E + 255) / 256), 256, 0, stream>>>(ei_raw, flags, ei32, 2 * E, N);

    int tiles = (N + 15) / 16;
    k_hw<<<dim3((tiles + 3) / 4), 256, 0, stream>>>(Hin, W, flags, Hw, N);
    k_scores<<<dim3((N * 4 + 255) / 256), 256, 0, stream>>>(Hw, Asrc, Atgt, flags, s_src,
                                                            s_tgt, N);
    k_deg<<<dim3((E + 255) / 256), 256, 0, stream>>>(ei32, deg, E);
    int nb = (N + 255) / 256;
    k_blocksum<<<dim3(nb), 256, 0, stream>>>(deg, part, N);
    k_scanpart<<<dim3(1), 512, 0, stream>>>(part, psum, nb);
    k_offsets<<<dim3(nb), 256, 0, stream>>>(deg, psum, offs, cursor, N);
    k_fill<<<dim3((E + 255) / 256), 256, 0, stream>>>(ei32, cursor, csr, E);
    k_aggr<<<dim3((N + 3) / 4), 256, 0, stream>>>(offs, csr, s_src, s_tgt, Hw, flags, d_out, N);
}